// Round 9
// baseline (181.045 us; speedup 1.0000x reference)
//
#include <hip/hip_runtime.h>
#include <hip/hip_bf16.h>
#include <cstdint>

#define BATCH 4096
#define INF   1024
#define OUTF  1024
#define LCH   12              // 11 spline channels + 1 base channel
#define KTOT  (INF*LCH)       // 12288
#define KHALF (KTOT/2)        // 6144
#define IHALF (INF/2)         // 512

#define BM 256
#define BN 128
#define IC 8                  // features per K-tile
#define BK (IC*LCH)           // 96 k per K-tile
#define NCHUNK (IHALF/IC)     // 64 K-tiles per k-half
#define NGRAN (BK/8)          // 12 k-granules per K-tile
#define THREADS 512
#define ABUF (NGRAN*256*8)    // 24576 ushorts = 48 KB
#define BBUF (NGRAN*128*8)    // 12288 ushorts = 24 KB

#define WT_BYTES   ((size_t)OUTF * KTOT * 2)          // 25165824
#define OUT_BYTES  ((size_t)BATCH * OUTF * 4)         // 16777216

typedef __bf16 bf16x8 __attribute__((ext_vector_type(8)));
typedef float  f32x4  __attribute__((ext_vector_type(4)));
typedef unsigned long long ull;

struct alignas(16) U2 { ull x, y; };

__device__ __forceinline__ unsigned short f2bf(float f) {
  unsigned int u = __builtin_bit_cast(unsigned int, f);
  u += 0x7FFFu + ((u >> 16) & 1u);
  return (unsigned short)(u >> 16);
}

__device__ __forceinline__ void async_copy16(const void* g, void* l) {
  __builtin_amdgcn_global_load_lds(
      (const __attribute__((address_space(1))) unsigned int*)g,
      (__attribute__((address_space(3))) unsigned int*)l,
      16, 0, 0);
}

#define WAIT_VM(N) do {                                            \
  asm volatile("s_waitcnt vmcnt(" #N ")" ::: "memory");            \
  __builtin_amdgcn_sched_barrier(0);                               \
} while (0)

#define WAIT_LGKM0() do {                                          \
  asm volatile("s_waitcnt lgkmcnt(0)" ::: "memory");               \
  __builtin_amdgcn_sched_barrier(0);                               \
} while (0)

#define BARRIER() __builtin_amdgcn_s_barrier()

// ---------------- kernel 1: weights f32 -> bf16, k = i*12 + l ----------------
__global__ __launch_bounds__(256) void kan_build_wt(
    const float* __restrict__ sw,        // [OUTF][INF][11]
    const float* __restrict__ bw,        // [OUTF][INF]
    unsigned short* __restrict__ Wt)     // [OUTF][KTOT] bf16
{
  int idx = blockIdx.x * 256 + threadIdx.x;
  int o = idx >> 10;
  int i = idx & 1023;
  const float* s = sw + (size_t)(o * 1024 + i) * 11;
  unsigned short v[12];
#pragma unroll
  for (int l = 0; l < 11; ++l) v[l] = f2bf(s[l]);
  v[11] = f2bf(bw[o * 1024 + i]);
  unsigned short* d = Wt + (size_t)o * KTOT + i * 12;
  *reinterpret_cast<ushort4*>(d + 0) = make_ushort4(v[0], v[1], v[2],  v[3]);
  *reinterpret_cast<ushort4*>(d + 4) = make_ushort4(v[4], v[5], v[6],  v[7]);
  *reinterpret_cast<ushort4*>(d + 8) = make_ushort4(v[8], v[9], v[10], v[11]);
}

// -- kernel 2: 256x128 tile, k-split x2, 3-phase m201-style schedule ----------
template <bool USE_ATOMIC>
__global__ __launch_bounds__(THREADS, 2) void kan_gemm(
    const float* __restrict__ x,             // [BATCH][INF]
    const unsigned short* __restrict__ Wt,   // [OUTF][KTOT] bf16
    float* __restrict__ out,                 // [BATCH][OUTF]
    float* __restrict__ partial)             // [BATCH][OUTF] (k-half 1)
{
  // A dbuf [12][256][8], B dbuf [12][128][8]  -> 144 KB total
  __shared__ alignas(16) unsigned short smem[2 * ABUF + 2 * BBUF];

  const int tid  = threadIdx.x;
  const int lane = tid & 63;
  const int wid  = tid >> 6;              // 0..7
  const int wm   = (wid >> 1) * 64;       // 4 wave-rows of 64
  const int wn   = (wid & 1) * 64;        // 2 wave-cols of 64
  const int lr   = lane & 15;
  const int lk   = lane >> 4;
  const int idx  = (int)blockIdx.x;       // 0..255
  const int bn   = idx & 7;               // 0..7  (== XCD id -> per-XCD Wt panel)
  const int kh   = (idx >> 3) & 1;        // k-half
  const int bm   = idx >> 4;              // 0..15

  // A-build mapping: thread -> (row ar, 4 features at af0)
  const int ar  = tid & 255;
  const int af0 = (tid >> 8) * 4;         // 0 or 4 (wave-uniform)
  const int gb  = (af0 >> 2) * 6;         // granule base: 0 or 6
  const float* xrow = x + (size_t)(bm * BM + ar) * INF + kh * IHALF + af0;
  const size_t kbase = (size_t)kh * KHALF;

  unsigned short* Acur = smem;
  unsigned short* Aalt = smem + ABUF;
  unsigned short* Bcur = smem + 2 * ABUF;
  unsigned short* Balt = smem + 2 * ABUF + BBUF;

  f32x4 acc[4][4] = {};

  auto stageB = [&](int c, unsigned short* Bd) {
#pragma unroll
    for (int qq = 0; qq < 3; ++qq) {
      int G  = (wid * 3 + qq) * 64 + lane;   // granule 0..1535 (linear dest, DMA rule)
      int kk = G >> 7;                       // 0..11
      int oo = G & 127;
      const unsigned short* src =
          Wt + (size_t)(bn * BN + oo) * KTOT + kbase + c * BK + kk * 8;
      async_copy16(src, Bd + (wid * 3 + qq) * 512);   // wave-uniform base; HW adds lane*16
    }
  };

  // build 2 features (24 k = 3 granules) at granule base g0
  auto buildA2 = [&](float x0, float x1, unsigned short* Ad, int g0) {
    ull W[6];
#pragma unroll
    for (int j = 0; j < 2; ++j) {
      float xx = (j == 0) ? x0 : x1;
      float u  = fmaf(xx, 4.0f, 7.0f);       // in (3,11); x in (-1,1)
      float fm = floorf(u);
      int   mi = (int)fm;                    // 3..10
      float t  = u - fm;
      float s  = 1.0f - t;
      float t2 = t * t, t3 = t2 * t;
      float w0 = (s * s * s) * (1.0f / 6.0f);
      float w3 = t3 * (1.0f / 6.0f);
      float w1 = fmaf(0.5f, t3, 2.0f / 3.0f) - t2;
      float w2 = 1.0f - w0 - w1 - w3;
      int ls = mi - 3;                       // 0..7

      unsigned int p01, p23;                 // packed bf16 pairs (RNE)
      asm("v_cvt_pk_bf16_f32 %0, %1, %2" : "=v"(p01) : "v"(w0), "v"(w1));
      asm("v_cvt_pk_bf16_f32 %0, %1, %2" : "=v"(p23) : "v"(w2), "v"(w3));
      ull W64 = (ull)p01 | ((ull)p23 << 32);

      int sh = ls << 4;                      // 0..112
      int a  = sh & 63;
      ull lop  = W64 << a;
      ull hip_ = a ? (W64 >> (64 - a)) : 0ull;
      W[3 * j + 0] = (sh < 64) ? lop : 0ull;
      W[3 * j + 1] = (sh < 64) ? hip_ : lop;
      W[3 * j + 2] = ((sh < 64) ? 0ull : hip_) | ((ull)f2bf(xx) << 48); // slot 11 = x
    }
    U2* p = reinterpret_cast<U2*>(Ad);
    U2 u0; u0.x = W[0]; u0.y = W[1];
    U2 u1; u1.x = W[2]; u1.y = W[3];
    U2 u2; u2.x = W[4]; u2.y = W[5];
    p[(g0 + 0) * 256 + ar] = u0;             // lane-consecutive -> conflict-free
    p[(g0 + 1) * 256 + ar] = u1;
    p[(g0 + 2) * 256 + ar] = u2;
  };

  bf16x8 af[4], bfr[4];
  auto readFrags = [&](int p) {
    const int kk = p * 4 + lk;               // granule 0..11
#pragma unroll
    for (int mf = 0; mf < 4; ++mf)
      af[mf] = *reinterpret_cast<const bf16x8*>(
          &Acur[(kk * 256 + wm + mf * 16 + lr) * 8]);
#pragma unroll
    for (int nf = 0; nf < 4; ++nf)
      bfr[nf] = *reinterpret_cast<const bf16x8*>(
          &Bcur[(kk * 128 + wn + nf * 16 + lr) * 8]);
  };
  auto doMFMA = [&]() {
    __builtin_amdgcn_s_setprio(1);
#pragma unroll
    for (int mf = 0; mf < 4; ++mf)
#pragma unroll
      for (int nf = 0; nf < 4; ++nf)
        acc[mf][nf] = __builtin_amdgcn_mfma_f32_16x16x32_bf16(
            af[mf], bfr[nf], acc[mf][nf], 0, 0, 0);
    __builtin_amdgcn_s_setprio(0);
  };

  // ---- prologue: A0 built, B0 staged, x(1) in flight ----
  {
    float4 x0 = *reinterpret_cast<const float4*>(xrow);   // waited (reg use)
    buildA2(x0.x, x0.y, Acur, gb + 0);
    buildA2(x0.z, x0.w, Acur, gb + 3);
    stageB(0, Bcur);                                      // 3 DMAs
  }
  float4 xa = *reinterpret_cast<const float4*>(xrow + IC);  // x of K-tile 1
  asm volatile("s_waitcnt vmcnt(1) lgkmcnt(0)" ::: "memory"); // B0 landed; keep xa
  __builtin_amdgcn_sched_barrier(0);
  BARRIER();

  for (int c = 0; c < NCHUNK; ++c) {
    const int cn = (c + 1 < NCHUNK) ? (c + 1) : (NCHUNK - 1);
    const int cf = (c + 2 < NCHUNK) ? (c + 2) : (NCHUNK - 1);

    // ---------------- phase 0 ----------------
    WAIT_VM(1);          // Bcur's 3 DMAs landed (keep newest x in flight)
    stageB(cn, Balt);    // 3 DMAs for next K-tile
    readFrags(0);
    BARRIER();
    WAIT_LGKM0();
    doMFMA();
    BARRIER();
    // ---------------- phase 1 ----------------
    buildA2(xa.x, xa.y, Aalt, gb + 0);   // A(c+1) first half
    readFrags(1);
    BARRIER();
    WAIT_LGKM0();
    doMFMA();
    BARRIER();
    // ---------------- phase 2 ----------------
    float4 xb = *reinterpret_cast<const float4*>(xrow + cf * IC);  // x(c+2)
    buildA2(xa.z, xa.w, Aalt, gb + 3);   // A(c+1) second half
    readFrags(2);
    BARRIER();
    WAIT_LGKM0();
    doMFMA();
    BARRIER();

    // rotate buffers
    unsigned short* t = Acur; Acur = Aalt; Aalt = t;
    t = Bcur; Bcur = Balt; Balt = t;
    xa = xb;
  }

  asm volatile("s_waitcnt vmcnt(0) lgkmcnt(0)" ::: "memory");

  // ---- epilogue: C/D col=lane&15, row=(lane>>4)*4+v (verified R1-R5) ----
  float* dst = (USE_ATOMIC || kh == 0) ? out : partial;
#pragma unroll
  for (int mf = 0; mf < 4; ++mf) {
#pragma unroll
    for (int v = 0; v < 4; ++v) {
      int row = bm * BM + wm + mf * 16 + lk * 4 + v;
      float* orow = dst + (size_t)row * OUTF + bn * BN + wn + lr;
#pragma unroll
      for (int nf = 0; nf < 4; ++nf) {
        if (USE_ATOMIC) atomicAdd(&orow[nf * 16], acc[mf][nf][v]);
        else            orow[nf * 16] = acc[mf][nf][v];
      }
    }
  }
}

// ---------------- kernel 3: out += partial (k-half merge) --------------------
__global__ __launch_bounds__(256) void kan_reduce(
    float4* __restrict__ out, const float4* __restrict__ p)
{
  int i = blockIdx.x * 256 + threadIdx.x;   // 0 .. 1048575
  float4 a = out[i], b = p[i];
  a.x += b.x; a.y += b.y; a.z += b.z; a.w += b.w;
  out[i] = a;
}

extern "C" void kernel_launch(void* const* d_in, const int* in_sizes, int n_in,
                              void* d_out, int out_size, void* d_ws, size_t ws_size,
                              hipStream_t stream) {
  const float* x  = (const float*)d_in[0];   // [4096][1024]
  const float* bw = (const float*)d_in[1];   // [1024][1024]
  const float* sw = (const float*)d_in[2];   // [1024][1024][11]
  float* out = (float*)d_out;

  unsigned short* Wt = (unsigned short*)d_ws;
  if (ws_size < WT_BYTES) return;

  kan_build_wt<<<(OUTF * INF) / 256, 256, 0, stream>>>(sw, bw, Wt);

  if (ws_size >= WT_BYTES + OUT_BYTES) {
    float* partial = (float*)((char*)d_ws + WT_BYTES);
    kan_gemm<false><<<256, THREADS, 0, stream>>>(x, Wt, out, partial);
    kan_reduce<<<(BATCH * OUTF / 4) / 256, 256, 0, stream>>>(
        (float4*)out, (const float4*)partial);
  } else {
    hipMemsetAsync(d_out, 0, OUT_BYTES, stream);
    kan_gemm<true><<<256, THREADS, 0, stream>>>(x, Wt, out, out);
  }
}